// Round 7
// baseline (376.434 us; speedup 1.0000x reference)
//
#include <hip/hip_runtime.h>
#include <hip/hip_bf16.h>

typedef float f32x4 __attribute__((ext_vector_type(4)));
typedef __bf16 bf16x4 __attribute__((ext_vector_type(4)));
typedef __bf16 bf16x8 __attribute__((ext_vector_type(8)));

__device__ __forceinline__ void gld_lds16(const void* g, void* l) {
  __builtin_amdgcn_global_load_lds((const __attribute__((address_space(1))) void*)g,
                                   (__attribute__((address_space(3))) void*)l, 16, 0, 0);
}

// ---------------------------------------------------------------------------
__global__ void cvt_f32_bf16(const float* __restrict__ in, __bf16* __restrict__ out,
                             int n8) {
  int idx = blockIdx.x * blockDim.x + threadIdx.x;
  if (idx >= n8) return;
  f32x4 a = *(const f32x4*)(in + (size_t)idx * 8);
  f32x4 b = *(const f32x4*)(in + (size_t)idx * 8 + 4);
  bf16x8 o;
#pragma unroll
  for (int j = 0; j < 4; ++j) { o[j] = (__bf16)a[j]; o[4 + j] = (__bf16)b[j]; }
  *(bf16x8*)(out + (size_t)idx * 8) = o;
}

// ---------------------------------------------------------------------------
__global__ void build_trig(float* __restrict__ trig) {
  int idx = blockIdx.x * blockDim.x + threadIdx.x;
  if (idx >= 2048 * 64) return;
  int i = idx & 63, s = idx >> 6;
  float ang = (float)s * powf(10000.0f, -(float)i * (1.0f / 64.0f));
  float sn, cs;
  sincosf(ang, &sn, &cs);
  trig[idx * 2] = cs;
  trig[idx * 2 + 1] = sn;
}

// ---------------------------------------------------------------------------
__global__ void rope_bf16(__bf16* __restrict__ T, const float* __restrict__ trig,
                          int stride, int nh_mask, int nh_shift, float mul, int total) {
  int idx = blockIdx.x * blockDim.x + threadIdx.x;
  if (idx >= total) return;
  int i = idx & 63;
  int h = (idx >> 6) & nh_mask;
  int s = idx >> (6 + nh_shift);
  float cs = trig[(s * 64 + i) * 2];
  float sn = trig[(s * 64 + i) * 2 + 1];
  __bf16* p = T + (size_t)s * stride + h * 128 + 2 * i;
  float e = (float)p[0], o = (float)p[1];
  p[0] = (__bf16)((e * cs - o * sn) * mul);
  p[1] = (__bf16)((e * sn + o * cs) * mul);
}

// ---------------------------------------------------------------------------
__global__ __launch_bounds__(256) void transpose_v(const __bf16* __restrict__ KVb,
                                                   __bf16* __restrict__ Vt) {
  __shared__ __bf16 T[64][72];
  const int tid = threadIdx.x;
  const int s0 = blockIdx.x * 64, d0 = blockIdx.y * 64;
  const int r = tid >> 3, c8 = (tid & 7) * 8;
#pragma unroll
  for (int i = 0; i < 2; ++i) {
    int row = i * 32 + r;
    *(bf16x8*)&T[row][c8] = *(const bf16x8*)&KVb[(size_t)(s0 + row) * 2048 + 1024 + d0 + c8];
  }
  __syncthreads();
#pragma unroll
  for (int i = 0; i < 2; ++i) {
    int drow = i * 32 + r;
    bf16x8 o;
#pragma unroll
    for (int j = 0; j < 8; ++j) o[j] = T[c8 + j][drow];
    *(bf16x8*)&Vt[(size_t)(d0 + drow) * 2048 + s0 + c8] = o;
  }
}

// ---------------------------------------------------------------------------
// GEMM  C[M][N] = A[M][K] @ B[N][K]^T, bf16 in, OutT out.  (unchanged R5)
// ---------------------------------------------------------------------------
template <int BM, int BN, typename OutT>
__global__ __launch_bounds__(256) void gemm_bf16(const __bf16* __restrict__ A,
                                                 const __bf16* __restrict__ B0,
                                                 const __bf16* __restrict__ B1,
                                                 int Nsplit, OutT* __restrict__ C,
                                                 int M, int N, int K) {
  constexpr int MI = BM / 32, NJ = BN / 32;
  constexpr int RA = BM / 32, RB = BN / 32;
  __shared__ __bf16 As[BM * 64] __attribute__((aligned(16)));
  __shared__ __bf16 Bs[BN * 64] __attribute__((aligned(16)));

  const int tid = threadIdx.x;
  const int lane = tid & 63;
  const int w = tid >> 6;
  const int nwg = gridDim.x * gridDim.y;
  const int orig = blockIdx.y * gridDim.x + blockIdx.x;
  const int wgid = (orig & 7) * (nwg >> 3) + (orig >> 3);
  const int m0 = (wgid % gridDim.x) * BM;
  const int n0 = (wgid / gridDim.x) * BN;
  const int li = lane & 15, lg = lane >> 4;

  const __bf16* bsrc[RB];
#pragma unroll
  for (int i = 0; i < RB; ++i) {
    int slot = i * 256 + w * 64 + lane;
    int row = slot >> 3;
    int sch = (slot & 7) ^ (row & 7);
    int n = n0 + row;
    bsrc[i] = (n < Nsplit ? B0 + (size_t)n * K : B1 + (size_t)(n - Nsplit) * K) +
              sch * 8;
  }
  const __bf16* asrc[RA];
#pragma unroll
  for (int i = 0; i < RA; ++i) {
    int slot = i * 256 + w * 64 + lane;
    int row = slot >> 3;
    int sch = (slot & 7) ^ (row & 7);
    asrc[i] = A + (size_t)(m0 + row) * K + sch * 8;
  }

  const int wr = (w >> 1) * (BM / 2);
  const int wc = (w & 1) * (BN / 2);

  f32x4 acc[MI][NJ] = {};

  for (int k0 = 0; k0 < K; k0 += 64) {
    __syncthreads();
#pragma unroll
    for (int i = 0; i < RA; ++i)
      gld_lds16(asrc[i] + k0, &As[(i * 256 + w * 64) * 8]);
#pragma unroll
    for (int i = 0; i < RB; ++i)
      gld_lds16(bsrc[i] + k0, &Bs[(i * 256 + w * 64) * 8]);
    __syncthreads();

#pragma unroll
    for (int u = 0; u < 2; ++u) {
      bf16x8 af[MI], bfr[NJ];
#pragma unroll
      for (int mi = 0; mi < MI; ++mi)
        af[mi] = *(const bf16x8*)&As[(wr + mi * 16 + li) * 64 +
                                     (((u * 4 + lg) ^ (li & 7)) * 8)];
#pragma unroll
      for (int nj = 0; nj < NJ; ++nj)
        bfr[nj] = *(const bf16x8*)&Bs[(wc + nj * 16 + li) * 64 +
                                      (((u * 4 + lg) ^ (li & 7)) * 8)];
#pragma unroll
      for (int mi = 0; mi < MI; ++mi)
#pragma unroll
        for (int nj = 0; nj < NJ; ++nj)
          acc[mi][nj] = __builtin_amdgcn_mfma_f32_16x16x32_bf16(af[mi], bfr[nj],
                                                                acc[mi][nj], 0, 0, 0);
    }
  }

  const int crow = lg * 4;
#pragma unroll
  for (int mi = 0; mi < MI; ++mi)
#pragma unroll
    for (int nj = 0; nj < NJ; ++nj)
#pragma unroll
      for (int r = 0; r < 4; ++r)
        C[(size_t)(m0 + wr + mi * 16 + crow + r) * N + (n0 + wc + nj * 16 + li)] =
            (OutT)acc[mi][nj][r];
}

// ---------------------------------------------------------------------------
// Causal GQA flash attention v5.
// vs v4: swapped QK^T (mfma(K,Q): C row=key col=q -> P store is 8x
// ds_write_b64 instead of 32x ds_write_b16), counted-vmcnt raw barriers
// (K(t+1) prefetch stays in flight through PV; no vmcnt(0) in loop),
// s_setprio around MFMA clusters.
// FIFO accounting per tile: issue V(t) then K(t+1) (dummy K on last tile
// keeps counts uniform): at QK outstanding=[K(t)4][V(t)4][K(t+1)4] ->
// vmcnt(8)=K(t) done; at PV vmcnt(4)=V(t) done; end barrier plain.
// ---------------------------------------------------------------------------
__global__ __launch_bounds__(256) void attn_fwd_v5(const __bf16* __restrict__ Q,
                                                   const __bf16* __restrict__ KVb,
                                                   const __bf16* __restrict__ Vt,
                                                   __bf16* __restrict__ O) {
  const int tid = threadIdx.x;
  const int lane = tid & 63;
  const int w = tid >> 6;
  const int orig = blockIdx.x;
  const int chunk = orig & 7;       // XCD owns kvh group
  const int wkk = orig >> 3;        // 0..31
  const int h = chunk * 4 + (wkk & 3);
  const int pair = wkk >> 2;        // 0..7
  const int kvh = h >> 2;

  __shared__ __bf16 Ks[2][64 * 128] __attribute__((aligned(16)));
  __shared__ __bf16 Vts[128 * 64] __attribute__((aligned(16)));
  __shared__ __bf16 Ps[4][32 * 72] __attribute__((aligned(16)));

  const int li = lane & 15, lg = lane >> 4;

  auto stage_k = [&](int k0, int buf) {
#pragma unroll
    for (int i = 0; i < 4; ++i) {
      int slot = i * 256 + tid;
      int row = slot >> 4;
      int sch = (slot & 15) ^ (row & 7);
      gld_lds16(&KVb[(size_t)(k0 + row) * 2048 + kvh * 128 + sch * 8],
                &Ks[buf][(i * 256 + w * 64) * 8]);
    }
  };
  auto stage_v = [&](int k0) {
#pragma unroll
    for (int i = 0; i < 4; ++i) {
      int slot = i * 256 + tid;
      int row = slot >> 3;
      int sch = (slot & 7) ^ (row & 7);
      gld_lds16(&Vt[(size_t)(kvh * 128 + row) * 2048 + k0 + sch * 8],
                &Vts[(i * 256 + w * 64) * 8]);
    }
  };

#pragma unroll 1
  for (int pass = 0; pass < 2; ++pass) {
    const int m0 = ((pass == 0) ? (15 - pair) : pair) * 128;
    const int rbase = m0 + w * 32;

    bf16x8 qf[2][4];
#pragma unroll
    for (int mt = 0; mt < 2; ++mt) {
      const __bf16* qrow = Q + (size_t)(rbase + mt * 16 + li) * 4096 + h * 128;
#pragma unroll
      for (int kc = 0; kc < 4; ++kc) qf[mt][kc] = *(const bf16x8*)(qrow + kc * 32 + lg * 8);
    }

    f32x4 accO[2][8] = {};
    float plane[2] = {0.f, 0.f};

    const int wmax = rbase + 31;
    const int ntile = (m0 + 128) >> 6;

    stage_k(0, 0);

#pragma unroll 1
    for (int t = 0; t < ntile; ++t) {
      const int k0 = t * 64;
      const int cur = t & 1;
      stage_v(k0);
      stage_k(t + 1 < ntile ? k0 + 64 : 0, cur ^ 1);  // dummy on last: uniform FIFO

      asm volatile("s_waitcnt vmcnt(8)" ::: "memory");  // K(t) landed (all my loads but newest 8)
      __builtin_amdgcn_s_barrier();                     // -> all waves' K(t) DMAs done
      __builtin_amdgcn_sched_barrier(0);
      asm volatile("" ::: "memory");

      const bool active = (k0 <= wmax);
      bf16x8 pa[2][2];
      if (active) {
        // ---- QK^T swapped: s2[nt][mt] rows=key(lg*4+r), cols=q(li) ----
        f32x4 s2[4][2] = {};
        __builtin_amdgcn_s_setprio(1);
#pragma unroll
        for (int nt = 0; nt < 4; ++nt)
#pragma unroll
          for (int kc = 0; kc < 4; ++kc) {
            bf16x8 kf = *(const bf16x8*)&Ks[cur][(li + 16 * nt) * 128 +
                                                (((4 * kc + lg) ^ (li & 7)) * 8)];
            s2[nt][0] = __builtin_amdgcn_mfma_f32_16x16x32_bf16(kf, qf[0][kc], s2[nt][0], 0, 0, 0);
            s2[nt][1] = __builtin_amdgcn_mfma_f32_16x16x32_bf16(kf, qf[1][kc], s2[nt][1], 0, 0, 0);
          }
        __builtin_amdgcn_s_setprio(0);

        // ---- static-max softmax; P store contiguous-in-key (b64) ----
#pragma unroll
        for (int mt = 0; mt < 2; ++mt) {
          const int qb = rbase + mt * 16;
          const int q = qb + li;  // this lane's q-column
          const bool needmask = (k0 + 63 > qb);
#pragma unroll
          for (int nt = 0; nt < 4; ++nt) {
            bf16x4 pk;
#pragma unroll
            for (int r = 0; r < 4; ++r) {
              const int key = k0 + 16 * nt + lg * 4 + r;
              float v = s2[nt][mt][r];
              if (needmask && key > q) v = -INFINITY;
              float p = exp2f(v);
              plane[mt] += p;
              pk[r] = (__bf16)p;
            }
            *(bf16x4*)&Ps[w][(mt * 16 + li) * 72 + 16 * nt + lg * 4] = pk;
          }
          pa[mt][0] = *(const bf16x8*)&Ps[w][(mt * 16 + li) * 72 + lg * 8];
          pa[mt][1] = *(const bf16x8*)&Ps[w][(mt * 16 + li) * 72 + 32 + lg * 8];
        }
      }

      asm volatile("s_waitcnt vmcnt(4)" ::: "memory");  // V(t) landed; K(t+1) still in flight
      __builtin_amdgcn_s_barrier();
      __builtin_amdgcn_sched_barrier(0);
      asm volatile("" ::: "memory");

      if (active) {
        __builtin_amdgcn_s_setprio(1);
#pragma unroll
        for (int dt = 0; dt < 8; ++dt)
#pragma unroll
          for (int kc = 0; kc < 2; ++kc) {
            bf16x8 vf = *(const bf16x8*)&Vts[(li + 16 * dt) * 64 +
                                             (((4 * kc + lg) ^ (li & 7)) * 8)];
            accO[0][dt] = __builtin_amdgcn_mfma_f32_16x16x32_bf16(pa[0][kc], vf, accO[0][dt], 0, 0, 0);
            accO[1][dt] = __builtin_amdgcn_mfma_f32_16x16x32_bf16(pa[1][kc], vf, accO[1][dt], 0, 0, 0);
          }
        __builtin_amdgcn_s_setprio(0);
      }

      __builtin_amdgcn_s_barrier();   // PV reads done before next tile's DMAs
      __builtin_amdgcn_sched_barrier(0);
      asm volatile("" ::: "memory");
    }

    // ---- epilogue: reduce plane over lg-dups, redistribute, normalize ----
#pragma unroll
    for (int mt = 0; mt < 2; ++mt) {
      float sum = plane[mt];
      sum += __shfl_xor(sum, 16);
      sum += __shfl_xor(sum, 32);   // all lanes with same li now hold total for q=qb+li
      float inv[4];
#pragma unroll
      for (int r = 0; r < 4; ++r) inv[r] = 1.0f / __shfl(sum, lg * 4 + r);
#pragma unroll
      for (int dt = 0; dt < 8; ++dt)
#pragma unroll
        for (int r = 0; r < 4; ++r)
          O[(size_t)(rbase + mt * 16 + lg * 4 + r) * 4096 + h * 128 + dt * 16 + li] =
              (__bf16)(accO[mt][dt][r] * inv[r]);
    }
  }
}

// ---------------------------------------------------------------------------
extern "C" void kernel_launch(void* const* d_in, const int* in_sizes, int n_in,
                              void* d_out, int out_size, void* d_ws, size_t ws_size,
                              hipStream_t stream) {
  const float* x  = (const float*)d_in[0];
  const float* wq = (const float*)d_in[1];
  const float* wk = (const float*)d_in[2];
  const float* wv = (const float*)d_in[3];
  const float* wo = (const float*)d_in[4];
  float* out = (float*)d_out;

  const int S = 2048, D = 4096;
  char* ws = (char*)d_ws;
  __bf16* xb  = (__bf16*)ws;                      // 16 MB (reused as AOb)
  __bf16* Qb  = (__bf16*)(ws + 16777216);         // 16 MB
  __bf16* KVb = (__bf16*)(ws + 33554432);         //  8 MB [2048][2048] K|V
  __bf16* Vt  = (__bf16*)(ws + 41943040);         //  4 MB [1024][2048]
  __bf16* wb  = (__bf16*)(ws + 46137344);         // 32 MB weight scratch
  float*  trig = (float*)(ws + 79691776);         //  1 MB
  __bf16* AOb = xb;

  // 1/sqrt(128) * log2(e): scores in log2 domain -> p = exp2(s)
  const float qscale = 0.08838834764831845f * 1.4426950408889634f;

  cvt_f32_bf16<<<(S * D / 8 + 255) / 256, 256, 0, stream>>>(x, xb, S * D / 8);
  cvt_f32_bf16<<<(D * D / 8 + 255) / 256, 256, 0, stream>>>(wq, wb, D * D / 8);
  gemm_bf16<128, 128, __bf16><<<dim3(16, 32), 256, 0, stream>>>(
      xb, wb, wb, 1 << 30, Qb, S, D, D);

  cvt_f32_bf16<<<(1024 * D / 8 + 255) / 256, 256, 0, stream>>>(wk, wb, 1024 * D / 8);
  cvt_f32_bf16<<<(1024 * D / 8 + 255) / 256, 256, 0, stream>>>(wv, wb + (size_t)1024 * D,
                                                               1024 * D / 8);
  gemm_bf16<64, 128, __bf16><<<dim3(32, 16), 256, 0, stream>>>(
      xb, wb, wb + (size_t)1024 * D, 1024, KVb, S, 2048, D);

  build_trig<<<(2048 * 64 + 255) / 256, 256, 0, stream>>>(trig);
  rope_bf16<<<(S * 32 * 64 + 255) / 256, 256, 0, stream>>>(Qb, trig, 4096, 31, 5,
                                                           qscale, S * 32 * 64);
  rope_bf16<<<(S * 8 * 64 + 255) / 256, 256, 0, stream>>>(KVb, trig, 2048, 7, 3,
                                                          1.0f, S * 8 * 64);
  transpose_v<<<dim3(32, 16), 256, 0, stream>>>(KVb, Vt);

  attn_fwd_v5<<<256, 256, 0, stream>>>(Qb, KVb, Vt, AOb);

  cvt_f32_bf16<<<(D * D / 8 + 255) / 256, 256, 0, stream>>>(wo, wb, D * D / 8);
  gemm_bf16<128, 128, float><<<dim3(16, 32), 256, 0, stream>>>(
      AOb, wb, wb, 1 << 30, out, S, D, D);
}

// Round 8
// 364.799 us; speedup vs baseline: 1.0319x; 1.0319x over previous
//
#include <hip/hip_runtime.h>
#include <hip/hip_bf16.h>

typedef float f32x4 __attribute__((ext_vector_type(4)));
typedef __bf16 bf16x4 __attribute__((ext_vector_type(4)));
typedef __bf16 bf16x8 __attribute__((ext_vector_type(8)));

__device__ __forceinline__ void gld_lds16(const void* g, void* l) {
  __builtin_amdgcn_global_load_lds((const __attribute__((address_space(1))) void*)g,
                                   (__attribute__((address_space(3))) void*)l, 16, 0, 0);
}

// ---------------------------------------------------------------------------
__global__ void cvt_f32_bf16(const float* __restrict__ in, __bf16* __restrict__ out,
                             int n8) {
  int idx = blockIdx.x * blockDim.x + threadIdx.x;
  if (idx >= n8) return;
  f32x4 a = *(const f32x4*)(in + (size_t)idx * 8);
  f32x4 b = *(const f32x4*)(in + (size_t)idx * 8 + 4);
  bf16x8 o;
#pragma unroll
  for (int j = 0; j < 4; ++j) { o[j] = (__bf16)a[j]; o[4 + j] = (__bf16)b[j]; }
  *(bf16x8*)(out + (size_t)idx * 8) = o;
}

// ---------------------------------------------------------------------------
__global__ void build_trig(float* __restrict__ trig) {
  int idx = blockIdx.x * blockDim.x + threadIdx.x;
  if (idx >= 2048 * 64) return;
  int i = idx & 63, s = idx >> 6;
  float ang = (float)s * powf(10000.0f, -(float)i * (1.0f / 64.0f));
  float sn, cs;
  sincosf(ang, &sn, &cs);
  trig[idx * 2] = cs;
  trig[idx * 2 + 1] = sn;
}

// ---------------------------------------------------------------------------
__global__ void rope_bf16(__bf16* __restrict__ T, const float* __restrict__ trig,
                          int stride, int nh_mask, int nh_shift, float mul, int total) {
  int idx = blockIdx.x * blockDim.x + threadIdx.x;
  if (idx >= total) return;
  int i = idx & 63;
  int h = (idx >> 6) & nh_mask;
  int s = idx >> (6 + nh_shift);
  float cs = trig[(s * 64 + i) * 2];
  float sn = trig[(s * 64 + i) * 2 + 1];
  __bf16* p = T + (size_t)s * stride + h * 128 + 2 * i;
  float e = (float)p[0], o = (float)p[1];
  p[0] = (__bf16)((e * cs - o * sn) * mul);
  p[1] = (__bf16)((e * sn + o * cs) * mul);
}

// ---------------------------------------------------------------------------
__global__ __launch_bounds__(256) void transpose_v(const __bf16* __restrict__ KVb,
                                                   __bf16* __restrict__ Vt) {
  __shared__ __bf16 T[64][72];
  const int tid = threadIdx.x;
  const int s0 = blockIdx.x * 64, d0 = blockIdx.y * 64;
  const int r = tid >> 3, c8 = (tid & 7) * 8;
#pragma unroll
  for (int i = 0; i < 2; ++i) {
    int row = i * 32 + r;
    *(bf16x8*)&T[row][c8] = *(const bf16x8*)&KVb[(size_t)(s0 + row) * 2048 + 1024 + d0 + c8];
  }
  __syncthreads();
#pragma unroll
  for (int i = 0; i < 2; ++i) {
    int drow = i * 32 + r;
    bf16x8 o;
#pragma unroll
    for (int j = 0; j < 8; ++j) o[j] = T[c8 + j][drow];
    *(bf16x8*)&Vt[(size_t)(d0 + drow) * 2048 + s0 + c8] = o;
  }
}

// ---------------------------------------------------------------------------
// GEMM  C[M][N] = A[M][K] @ B[N][K]^T, bf16 in, OutT out.  (unchanged R5)
// ---------------------------------------------------------------------------
template <int BM, int BN, typename OutT>
__global__ __launch_bounds__(256) void gemm_bf16(const __bf16* __restrict__ A,
                                                 const __bf16* __restrict__ B0,
                                                 const __bf16* __restrict__ B1,
                                                 int Nsplit, OutT* __restrict__ C,
                                                 int M, int N, int K) {
  constexpr int MI = BM / 32, NJ = BN / 32;
  constexpr int RA = BM / 32, RB = BN / 32;
  __shared__ __bf16 As[BM * 64] __attribute__((aligned(16)));
  __shared__ __bf16 Bs[BN * 64] __attribute__((aligned(16)));

  const int tid = threadIdx.x;
  const int lane = tid & 63;
  const int w = tid >> 6;
  const int nwg = gridDim.x * gridDim.y;
  const int orig = blockIdx.y * gridDim.x + blockIdx.x;
  const int wgid = (orig & 7) * (nwg >> 3) + (orig >> 3);
  const int m0 = (wgid % gridDim.x) * BM;
  const int n0 = (wgid / gridDim.x) * BN;
  const int li = lane & 15, lg = lane >> 4;

  const __bf16* bsrc[RB];
#pragma unroll
  for (int i = 0; i < RB; ++i) {
    int slot = i * 256 + w * 64 + lane;
    int row = slot >> 3;
    int sch = (slot & 7) ^ (row & 7);
    int n = n0 + row;
    bsrc[i] = (n < Nsplit ? B0 + (size_t)n * K : B1 + (size_t)(n - Nsplit) * K) +
              sch * 8;
  }
  const __bf16* asrc[RA];
#pragma unroll
  for (int i = 0; i < RA; ++i) {
    int slot = i * 256 + w * 64 + lane;
    int row = slot >> 3;
    int sch = (slot & 7) ^ (row & 7);
    asrc[i] = A + (size_t)(m0 + row) * K + sch * 8;
  }

  const int wr = (w >> 1) * (BM / 2);
  const int wc = (w & 1) * (BN / 2);

  f32x4 acc[MI][NJ] = {};

  for (int k0 = 0; k0 < K; k0 += 64) {
    __syncthreads();
#pragma unroll
    for (int i = 0; i < RA; ++i)
      gld_lds16(asrc[i] + k0, &As[(i * 256 + w * 64) * 8]);
#pragma unroll
    for (int i = 0; i < RB; ++i)
      gld_lds16(bsrc[i] + k0, &Bs[(i * 256 + w * 64) * 8]);
    __syncthreads();

#pragma unroll
    for (int u = 0; u < 2; ++u) {
      bf16x8 af[MI], bfr[NJ];
#pragma unroll
      for (int mi = 0; mi < MI; ++mi)
        af[mi] = *(const bf16x8*)&As[(wr + mi * 16 + li) * 64 +
                                     (((u * 4 + lg) ^ (li & 7)) * 8)];
#pragma unroll
      for (int nj = 0; nj < NJ; ++nj)
        bfr[nj] = *(const bf16x8*)&Bs[(wc + nj * 16 + li) * 64 +
                                      (((u * 4 + lg) ^ (li & 7)) * 8)];
#pragma unroll
      for (int mi = 0; mi < MI; ++mi)
#pragma unroll
        for (int nj = 0; nj < NJ; ++nj)
          acc[mi][nj] = __builtin_amdgcn_mfma_f32_16x16x32_bf16(af[mi], bfr[nj],
                                                                acc[mi][nj], 0, 0, 0);
    }
  }

  const int crow = lg * 4;
#pragma unroll
  for (int mi = 0; mi < MI; ++mi)
#pragma unroll
    for (int nj = 0; nj < NJ; ++nj)
#pragma unroll
      for (int r = 0; r < 4; ++r)
        C[(size_t)(m0 + wr + mi * 16 + crow + r) * N + (n0 + wc + nj * 16 + li)] =
            (OutT)acc[mi][nj][r];
}

// ---------------------------------------------------------------------------
// Causal GQA flash attention v6.
// vs v5: 8 waves (512 thr) x 16 q-rows each; K AND V double-buffered with
// depth-1 prefetch -> 2 barriers + one vmcnt(4) per tile (no vmcnt(0));
// per-wave state halved. Uniform 34 tiles/block via (pair, 15-pair) passes.
// FIFO: 4 DMA issues per wave per tile; at the wait, outstanding = 8,
// vmcnt(4) leaves exactly the newest 4 (tile t+1's) in flight.
// ---------------------------------------------------------------------------
__global__ __launch_bounds__(512) void attn_fwd_v6(const __bf16* __restrict__ Q,
                                                   const __bf16* __restrict__ KVb,
                                                   const __bf16* __restrict__ Vt,
                                                   __bf16* __restrict__ O) {
  const int tid = threadIdx.x;
  const int lane = tid & 63;
  const int w = tid >> 6;           // 0..7
  const int orig = blockIdx.x;
  const int chunk = orig & 7;       // XCD owns kvh group
  const int wkk = orig >> 3;        // 0..31
  const int h = chunk * 4 + (wkk & 3);
  const int pair = wkk >> 2;        // 0..7
  const int kvh = h >> 2;

  __shared__ __bf16 Ks[2][64 * 128] __attribute__((aligned(16)));   // 32 KB
  __shared__ __bf16 Vts[2][128 * 64] __attribute__((aligned(16)));  // 32 KB
  __shared__ __bf16 Ps[8][16 * 72] __attribute__((aligned(16)));    // 18 KB

  const int li = lane & 15, lg = lane >> 4;

  auto stage_k = [&](int k0, int buf) {
#pragma unroll
    for (int i = 0; i < 2; ++i) {
      int slot = i * 512 + tid;
      int row = slot >> 4;                 // 0..63 key
      int sch = (slot & 15) ^ (row & 7);
      gld_lds16(&KVb[(size_t)(k0 + row) * 2048 + kvh * 128 + sch * 8],
                &Ks[buf][(i * 512 + w * 64) * 8]);
    }
  };
  auto stage_v = [&](int k0, int buf) {
#pragma unroll
    for (int i = 0; i < 2; ++i) {
      int slot = i * 512 + tid;
      int row = slot >> 3;                 // 0..127 d
      int sch = (slot & 7) ^ (row & 7);
      gld_lds16(&Vt[(size_t)(kvh * 128 + row) * 2048 + k0 + sch * 8],
                &Vts[buf][(i * 512 + w * 64) * 8]);
    }
  };

#pragma unroll 1
  for (int pass = 0; pass < 2; ++pass) {
    const int m0 = ((pass == 0) ? (15 - pair) : pair) * 128;
    const int rbase = m0 + w * 16;        // 16 rows per wave

    bf16x8 qf[4];
    {
      const __bf16* qrow = Q + (size_t)(rbase + li) * 4096 + h * 128;
#pragma unroll
      for (int kc = 0; kc < 4; ++kc) qf[kc] = *(const bf16x8*)(qrow + kc * 32 + lg * 8);
    }

    f32x4 accO[8] = {};
    float plane = 0.f;

    const int wmax = rbase + 15;
    const int ntile = (m0 + 128) >> 6;

    __builtin_amdgcn_s_barrier();   // prev pass/tile readers done with all buffers
    stage_v(0, 0);
    stage_k(0, 0);

#pragma unroll 1
    for (int t = 0; t < ntile; ++t) {
      const int k0 = t * 64;
      const int cur = t & 1;

      __builtin_amdgcn_s_barrier();       // (A) everyone done reading buf[cur^1]
      const int nk = (t + 1 < ntile) ? k0 + 64 : 0;  // dummy keeps FIFO uniform
      stage_v(nk, cur ^ 1);
      stage_k(nk, cur ^ 1);

      asm volatile("s_waitcnt vmcnt(4)" ::: "memory");  // my K(t),V(t) landed
      __builtin_amdgcn_s_barrier();                     // (B) whole tile staged
      __builtin_amdgcn_sched_barrier(0);
      asm volatile("" ::: "memory");

      if (k0 <= wmax) {
        // ---- QK^T swapped: rows=key, cols=q ----
        f32x4 s2[4] = {};
        __builtin_amdgcn_s_setprio(1);
#pragma unroll
        for (int nt = 0; nt < 4; ++nt)
#pragma unroll
          for (int kc = 0; kc < 4; ++kc) {
            bf16x8 kf = *(const bf16x8*)&Ks[cur][(li + 16 * nt) * 128 +
                                                (((4 * kc + lg) ^ (li & 7)) * 8)];
            s2[nt] = __builtin_amdgcn_mfma_f32_16x16x32_bf16(kf, qf[kc], s2[nt], 0, 0, 0);
          }
        __builtin_amdgcn_s_setprio(0);

        // ---- static-max softmax: p = exp2(s); per-lane partial row-sum ----
        const int q = rbase + li;
        const bool needmask = (k0 + 63 > rbase);
#pragma unroll
        for (int nt = 0; nt < 4; ++nt) {
          bf16x4 pk;
#pragma unroll
          for (int r = 0; r < 4; ++r) {
            const int key = k0 + 16 * nt + lg * 4 + r;
            float v = s2[nt][r];
            if (needmask && key > q) v = -INFINITY;
            float p = exp2f(v);
            plane += p;
            pk[r] = (__bf16)p;
          }
          *(bf16x4*)&Ps[w][li * 72 + 16 * nt + lg * 4] = pk;
        }
        bf16x8 pa[2];
        pa[0] = *(const bf16x8*)&Ps[w][li * 72 + lg * 8];
        pa[1] = *(const bf16x8*)&Ps[w][li * 72 + 32 + lg * 8];

        // ---- PV ----
        __builtin_amdgcn_s_setprio(1);
#pragma unroll
        for (int dt = 0; dt < 8; ++dt)
#pragma unroll
          for (int kc = 0; kc < 2; ++kc) {
            bf16x8 vf = *(const bf16x8*)&Vts[cur][(li + 16 * dt) * 64 +
                                                 (((4 * kc + lg) ^ (li & 7)) * 8)];
            accO[dt] = __builtin_amdgcn_mfma_f32_16x16x32_bf16(pa[kc], vf, accO[dt], 0, 0, 0);
          }
        __builtin_amdgcn_s_setprio(0);
      }
    }

    // ---- epilogue: reduce plane over lg-duplicates, normalize, store ----
    {
      float sum = plane;
      sum += __shfl_xor(sum, 16);
      sum += __shfl_xor(sum, 32);   // lanes sharing li hold total for q = rbase+li
      float inv[4];
#pragma unroll
      for (int r = 0; r < 4; ++r) inv[r] = 1.0f / __shfl(sum, lg * 4 + r);
#pragma unroll
      for (int dt = 0; dt < 8; ++dt)
#pragma unroll
        for (int r = 0; r < 4; ++r)
          O[(size_t)(rbase + lg * 4 + r) * 4096 + h * 128 + dt * 16 + li] =
              (__bf16)(accO[dt][r] * inv[r]);
    }
  }
}

// ---------------------------------------------------------------------------
extern "C" void kernel_launch(void* const* d_in, const int* in_sizes, int n_in,
                              void* d_out, int out_size, void* d_ws, size_t ws_size,
                              hipStream_t stream) {
  const float* x  = (const float*)d_in[0];
  const float* wq = (const float*)d_in[1];
  const float* wk = (const float*)d_in[2];
  const float* wv = (const float*)d_in[3];
  const float* wo = (const float*)d_in[4];
  float* out = (float*)d_out;

  const int S = 2048, D = 4096;
  char* ws = (char*)d_ws;
  __bf16* xb  = (__bf16*)ws;                      // 16 MB (reused as AOb)
  __bf16* Qb  = (__bf16*)(ws + 16777216);         // 16 MB
  __bf16* KVb = (__bf16*)(ws + 33554432);         //  8 MB [2048][2048] K|V
  __bf16* Vt  = (__bf16*)(ws + 41943040);         //  4 MB [1024][2048]
  __bf16* wb  = (__bf16*)(ws + 46137344);         // 32 MB weight scratch
  float*  trig = (float*)(ws + 79691776);         //  1 MB
  __bf16* AOb = xb;

  // 1/sqrt(128) * log2(e): scores in log2 domain -> p = exp2(s)
  const float qscale = 0.08838834764831845f * 1.4426950408889634f;

  cvt_f32_bf16<<<(S * D / 8 + 255) / 256, 256, 0, stream>>>(x, xb, S * D / 8);
  cvt_f32_bf16<<<(D * D / 8 + 255) / 256, 256, 0, stream>>>(wq, wb, D * D / 8);
  gemm_bf16<128, 128, __bf16><<<dim3(16, 32), 256, 0, stream>>>(
      xb, wb, wb, 1 << 30, Qb, S, D, D);

  cvt_f32_bf16<<<(1024 * D / 8 + 255) / 256, 256, 0, stream>>>(wk, wb, 1024 * D / 8);
  cvt_f32_bf16<<<(1024 * D / 8 + 255) / 256, 256, 0, stream>>>(wv, wb + (size_t)1024 * D,
                                                               1024 * D / 8);
  gemm_bf16<64, 128, __bf16><<<dim3(32, 16), 256, 0, stream>>>(
      xb, wb, wb + (size_t)1024 * D, 1024, KVb, S, 2048, D);

  build_trig<<<(2048 * 64 + 255) / 256, 256, 0, stream>>>(trig);
  rope_bf16<<<(S * 32 * 64 + 255) / 256, 256, 0, stream>>>(Qb, trig, 4096, 31, 5,
                                                           qscale, S * 32 * 64);
  rope_bf16<<<(S * 8 * 64 + 255) / 256, 256, 0, stream>>>(KVb, trig, 2048, 7, 3,
                                                          1.0f, S * 8 * 64);
  transpose_v<<<dim3(32, 16), 256, 0, stream>>>(KVb, Vt);

  attn_fwd_v6<<<256, 512, 0, stream>>>(Qb, KVb, Vt, AOb);

  cvt_f32_bf16<<<(D * D / 8 + 255) / 256, 256, 0, stream>>>(wo, wb, D * D / 8);
  gemm_bf16<128, 128, float><<<dim3(16, 32), 256, 0, stream>>>(
      AOb, wb, wb, 1 << 30, out, S, D, D);
}